// Round 1
// baseline (419.411 us; speedup 1.0000x reference)
//
#include <hip/hip_runtime.h>
#include <hip/hip_bf16.h>
#include <math.h>

// Problem constants (reference: B=8, S=1024, D=1024, E=8, F=2048, capacity 2 -> k=256)
#define B_   8
#define S_   1024
#define D_   1024
#define E_   8
#define F_   2048
#define KCAP 256

typedef __bf16 bf16x8 __attribute__((ext_vector_type(8)));
typedef float  floatx4 __attribute__((ext_vector_type(4)));
typedef unsigned short ushortx8 __attribute__((ext_vector_type(8)));

// ---- fp32 -> bf16 round-to-nearest-even (no NaN in this data) ----
__device__ __forceinline__ unsigned short f2b(float f) {
    union { float f; unsigned int u; } v; v.f = f;
    unsigned int u = v.u;
    u += 0x7fffu + ((u >> 16) & 1u);
    return (unsigned short)(u >> 16);
}
__device__ __forceinline__ float b2f(unsigned short u) {
    union { unsigned int u; float f; } v; v.u = ((unsigned)u) << 16; return v.f;
}

__device__ __forceinline__ void gl_lds16(const void* g, void* l) {
    __builtin_amdgcn_global_load_lds(
        (const __attribute__((address_space(1))) void*)g,
        (__attribute__((address_space(3))) void*)l, 16, 0, 0);
}

// sortable key: probs > 0 so float bits are monotonic; secondary index asc
// (larger (1023-s) wins ties -> smaller s, matching lax.top_k).
__device__ __forceinline__ unsigned long long topk_key(float p, int s) {
    return (((unsigned long long)__float_as_uint(p)) << 10) | (unsigned)(S_ - 1 - s);
}

// ---------------- 1. router: logits + softmax (fp32) + fused x->bf16 cast (vectorized) ----------------
// probs layout: [B][E][S] (transposed for per-(b,e) top-k). One wave per token; lane owns 4 consecutive d.
__global__ void router_kernel(const float* __restrict__ x, const float* __restrict__ cw,
                              float* __restrict__ probs, unsigned short* __restrict__ xb) {
    int gid  = blockIdx.x * 256 + threadIdx.x;
    int wave = gid >> 6;
    int lane = gid & 63;
    int b = wave >> 10;                                // S_=1024
    int s = wave & (S_ - 1);
    const float* xrow = x + ((size_t)b * S_ + s) * D_;
    unsigned short* xbrow = xb + ((size_t)b * S_ + s) * D_;
    float acc[E_];
#pragma unroll
    for (int e = 0; e < E_; e++) acc[e] = 0.f;
#pragma unroll
    for (int it = 0; it < D_ / 256; it++) {
        int i = it * 256 + lane * 4;
        float4 xv = *(const float4*)(xrow + i);
        ushort4 o;
        o.x = f2b(xv.x); o.y = f2b(xv.y); o.z = f2b(xv.z); o.w = f2b(xv.w);
        *(ushort4*)(xbrow + i) = o;                    // fused cast, 8B/lane stores
#pragma unroll
        for (int e = 0; e < E_; e++) {
            float4 wv = *(const float4*)(cw + e * D_ + i);   // 32KB table, L1/L2-resident
            acc[e] = fmaf(xv.x, wv.x, fmaf(xv.y, wv.y, fmaf(xv.z, wv.z, fmaf(xv.w, wv.w, acc[e]))));
        }
    }
#pragma unroll
    for (int e = 0; e < E_; e++) {
        float v = acc[e];
#pragma unroll
        for (int off = 32; off >= 1; off >>= 1) v += __shfl_down(v, off, 64);
        acc[e] = v;
    }
    if (lane == 0) {
        float m = acc[0];
#pragma unroll
        for (int e = 1; e < E_; e++) m = fmaxf(m, acc[e]);
        float sum = 0.f;
#pragma unroll
        for (int e = 0; e < E_; e++) { acc[e] = __expf(acc[e] - m); sum += acc[e]; }
        float inv = 1.f / sum;
#pragma unroll
        for (int e = 0; e < E_; e++) probs[((size_t)b * E_ + e) * S_ + s] = acc[e] * inv;
    }
}

// ---------------- 2. top-k (merged rank + finalize): one block per (b,e) ----------------
// Thread tid owns 4 candidates; all 1024 keys staged in LDS; rank = count of strictly-greater keys.
__global__ void topk_kernel(const float* __restrict__ probs, int* __restrict__ I,
                            float* __restrict__ G, unsigned short* __restrict__ Pmap) {
    const int be = blockIdx.x;
    const int b = be >> 3, e = be & 7;
    const int tid = threadIdx.x;
    __shared__ unsigned long long keys[S_];
    const float* rowp = probs + (size_t)be * S_;
#pragma unroll
    for (int q = 0; q < 4; q++) {
        const int s = q * 256 + tid;
        keys[s] = topk_key(rowp[s], s);
        Pmap[((size_t)(b * S_ + s)) * E_ + e] = 0;
    }
    __syncthreads();
    unsigned long long my[4];
    int r[4] = {0, 0, 0, 0};
#pragma unroll
    for (int q = 0; q < 4; q++) my[q] = keys[q * 256 + tid];
#pragma unroll 8
    for (int t = 0; t < S_; t++) {
        const unsigned long long kt = keys[t];                 // LDS broadcast
#pragma unroll
        for (int q = 0; q < 4; q++) r[q] += (kt > my[q]);
    }
#pragma unroll
    for (int q = 0; q < 4; q++) {
        if (r[q] < KCAP) {
            const int s = q * 256 + tid;
            I[be * KCAP + r[q]] = s;
            G[be * KCAP + r[q]] = rowp[s];
            Pmap[((size_t)(b * S_ + s)) * E_ + e] = (unsigned short)(r[q] + 1);
        }
    }
}

// ---------------- 3. batched transpose + cast: in [E][R][C] fp32 -> out [E][C][R] bf16 ----------------
__global__ void transpose_cvt_kernel(const float* __restrict__ in, unsigned short* __restrict__ out,
                                     int R, int C) {
    __shared__ float tile[32][33];                    // +1 pad
    int e = blockIdx.z;
    int c0 = blockIdx.x * 32, r0 = blockIdx.y * 32;
    const float* ine = in + (size_t)e * R * C;
    unsigned short* oute = out + (size_t)e * R * C;
    int tid = threadIdx.x;
    int row = tid >> 3, cs = tid & 7;
    float4 v = *(const float4*)(ine + (size_t)(r0 + row) * C + c0 + cs * 4);
    tile[row][cs * 4 + 0] = v.x; tile[row][cs * 4 + 1] = v.y;
    tile[row][cs * 4 + 2] = v.z; tile[row][cs * 4 + 3] = v.w;
    __syncthreads();
    int c = tid >> 3, rq = tid & 7;
    ushort4 o;
    o.x = f2b(tile[rq * 4 + 0][c]); o.y = f2b(tile[rq * 4 + 1][c]);
    o.z = f2b(tile[rq * 4 + 2][c]); o.w = f2b(tile[rq * 4 + 3][c]);
    *(ushort4*)(oute + (size_t)(c0 + c) * R + r0 + rq * 4) = o;
}

// ======== 8-phase 256x256 GEMM core (T2 swizzle + T3/T4 counted vmcnt + T5 setprio) ========
// 512 thr = 8 waves (2M x 4N), per-wave C = 128x64 (8x4 frags of 16x16x32 bf16 MFMA).
// LDS 128 KiB: A,B each [2 dbuf][2 half(128 rows)][128r][64k] bf16. Half-tile stage =
// 2 x global_load_lds dwordx4 / thread, linear dest, bank-conflict-free via 16B-segment
// permutation seg_stored = seg ^ (row & 7) (verified 0 conflicts in prior rounds).
// Schedule per iteration (2 K-tiles, t even; buf0 = tile t, buf1 = tile t+1):
//  ph1: rd A0-3,B0-1(buf0)  MFMA q(0,0)  stage A_hi(t+1)
//  ph2: rd A4-7,B2-3(buf0)  MFMA q(1,1)  stage B_hi(t+1)
//  ph3:                     MFMA q(0,1)  stage A_lo(t+2)
//  ph4:                     MFMA q(1,0)  stage B_lo(t+2)  vmcnt(4)
//  ph5..ph8: same on buf1 / tile t+1, staging A_hi/B_hi(t+2), A_lo/B_lo(t+3), vmcnt(4) at ph8.
// vmcnt(4) leaves exactly the 2 newest half-tiles in flight; every ds_read's source half-tile
// is >=2 half-tiles older than the wait point => landed (checked per-phase). WAR: each stage
// targets a region whose last ds_read was >=1 barrier earlier.

#define GBAR() __builtin_amdgcn_s_barrier()

#define LDA4(I0, BUF) do { \
    _Pragma("unroll") \
    for (int ii = 0; ii < 4; ii++) { \
        const int o_ = (BUF) * 16384 + aRd + ((I0) + ii) * 1024; \
        aF[(I0) + ii][0] = *(const bf16x8*)&Asm[o_]; \
        aF[(I0) + ii][1] = *(const bf16x8*)&Asm[o_ ^ 32]; \
    } } while (0)

#define LDB2(J0, BUF) do { \
    _Pragma("unroll") \
    for (int jj = 0; jj < 2; jj++) { \
        const int o_ = (BUF) * 16384 + bRd + ((J0) + jj) * 1024; \
        bF[(J0) + jj][0] = *(const bf16x8*)&Bsm[o_]; \
        bF[(J0) + jj][1] = *(const bf16x8*)&Bsm[o_ ^ 32]; \
    } } while (0)

#define MMQ(I0, J0) do { \
    __builtin_amdgcn_s_setprio(1); \
    _Pragma("unroll") \
    for (int ii = 0; ii < 4; ii++) \
    _Pragma("unroll") \
    for (int jj = 0; jj < 2; jj++) { \
        acc[(I0)+ii][(J0)+jj] = __builtin_amdgcn_mfma_f32_16x16x32_bf16(aF[(I0)+ii][0], bF[(J0)+jj][0], acc[(I0)+ii][(J0)+jj], 0, 0, 0); \
        acc[(I0)+ii][(J0)+jj] = __builtin_amdgcn_mfma_f32_16x16x32_bf16(aF[(I0)+ii][1], bF[(J0)+jj][1], acc[(I0)+ii][(J0)+jj], 0, 0, 0); \
    } \
    __builtin_amdgcn_s_setprio(0); \
} while (0)

#define STAGE_A(T, HH) do { if ((T) < NKT) { \
    const unsigned k_ = (unsigned)(T) * 64u; \
    const int d_ = ((((T) & 1) * 2 + (HH)) * 8192) + dst0; \
    gl_lds16(gA + srcA[(HH) * 2 + 0] + k_, &Asm[d_]); \
    gl_lds16(gA + srcA[(HH) * 2 + 1] + k_, &Asm[d_ + 4096]); \
} } while (0)

#define STAGE_B(T, HH) do { if ((T) < NKT) { \
    const unsigned k_ = (unsigned)(T) * 64u; \
    const int d_ = ((((T) & 1) * 2 + (HH)) * 8192) + dst0; \
    gl_lds16(gB + srcB[(HH) * 2 + 0] + k_, &Bsm[d_]); \
    gl_lds16(gB + srcB[(HH) * 2 + 1] + k_, &Bsm[d_ + 4096]); \
} } while (0)

// prologue: tile0 fully (8 loads) + tile1 lo halves (4 loads); wait 8 oldest -> tile0 landed.
#define PROLOGUE() do { \
    STAGE_A(0, 0); STAGE_A(0, 1); STAGE_B(0, 0); STAGE_B(0, 1); \
    STAGE_A(1, 0); STAGE_B(1, 0); \
    asm volatile("s_waitcnt vmcnt(4)" ::: "memory"); \
    GBAR(); \
} while (0)

#define KLOOP() \
    _Pragma("unroll 1") \
    for (int t = 0; t < NKT; t += 2) { \
        LDA4(0, 0); LDB2(0, 0); STAGE_A(t + 1, 1); \
        GBAR(); MMQ(0, 0); GBAR(); \
        LDA4(4, 0); LDB2(2, 0); STAGE_B(t + 1, 1); \
        GBAR(); MMQ(4, 2); GBAR(); \
        STAGE_A(t + 2, 0); \
        GBAR(); MMQ(0, 2); GBAR(); \
        STAGE_B(t + 2, 0); \
        if (t + 2 < NKT) { asm volatile("s_waitcnt vmcnt(4)" ::: "memory"); } \
        else             { asm volatile("s_waitcnt vmcnt(0)" ::: "memory"); } \
        GBAR(); MMQ(4, 0); GBAR(); \
        LDA4(0, 1); LDB2(0, 1); STAGE_A(t + 2, 1); \
        GBAR(); MMQ(0, 0); GBAR(); \
        LDA4(4, 1); LDB2(2, 1); STAGE_B(t + 2, 1); \
        GBAR(); MMQ(4, 2); GBAR(); \
        STAGE_A(t + 3, 0); \
        GBAR(); MMQ(0, 2); GBAR(); \
        STAGE_B(t + 3, 0); \
        asm volatile("s_waitcnt vmcnt(4)" ::: "memory"); \
        GBAR(); MMQ(4, 0); GBAR(); \
    }

// ---------------- 4. GEMM1: H[be] = silu(gather(x, I[be]) @ w1[e]) ----------------
__global__ __launch_bounds__(512, 2) void gemm1_kernel(
    const unsigned short* __restrict__ xb,   // [B][S][D] bf16
    const unsigned short* __restrict__ w1t,  // [E][F][D] bf16
    const int* __restrict__ Ibuf,            // [B][E][KCAP]
    unsigned short* __restrict__ H)          // [B*E][KCAP][F] bf16
{
    const int g  = blockIdx.x;               // 512 = e(8, XCD id) * b(8) * nt(8)
    const int e  = g & 7;
    const int rr = g >> 3;
    const int b  = rr >> 3;
    const int nt = rr & 7;
    const int be = b * 8 + e;
    const int tid = threadIdx.x;
    constexpr int NKT = D_ / 64;             // 16

    __shared__ __align__(16) unsigned short Asm[2 * 2 * 128 * 64];  // 64 KB
    __shared__ __align__(16) unsigned short Bsm[2 * 2 * 128 * 64];  // 64 KB

    const int r0   = tid >> 3;               // 0..63
    const int kseg = (tid & 7) ^ (r0 & 7);   // permuted 16B segment
    const int dst0 = tid * 8;                // LDS elem offset (w adds 4096)

    const unsigned short* gA = xb;
    const unsigned short* gB = w1t;
    unsigned srcA[4], srcB[4];               // rows r0 + {0,64,128,192}
#pragma unroll
    for (int q = 0; q < 4; q++) {
        const int m = q * 64 + r0;
        const int tok = Ibuf[be * KCAP + m];
        srcA[q] = (unsigned)((b * S_ + tok) * D_ + kseg * 8);
        srcB[q] = (unsigned)((e * F_ + nt * 256 + m) * D_ + kseg * 8);
    }

    const int lane = tid & 63;
    const int wv   = tid >> 6;
    const int wm2  = wv >> 2;                // 0..1
    const int wn4  = wv & 3;                 // 0..3
    const int l15  = lane & 15;
    const int quad = lane >> 4;
    const int x0   = (quad ^ (l15 & 7)) * 8;
    const int aRd  = wm2 * 8192 + l15 * 64 + x0;                    // + buf*16384 + i*1024
    const int bRd  = (wn4 >> 1) * 8192 + ((wn4 & 1) * 64 + l15) * 64 + x0;

    floatx4 acc[8][4];
#pragma unroll
    for (int i = 0; i < 8; i++)
#pragma unroll
        for (int j = 0; j < 4; j++) acc[i][j] = (floatx4){0.f, 0.f, 0.f, 0.f};
    bf16x8 aF[8][2], bF[4][2];

    PROLOGUE();
    KLOOP();

    // epilogue: silu -> H (bf16). C/D layout: row = quad*4+r, col = lane&15 (m89-verified)
    unsigned short* Hbe = H + (size_t)be * KCAP * F_ + (nt * 256 + wn4 * 64);
#pragma unroll
    for (int i = 0; i < 8; i++) {
#pragma unroll
        for (int r2 = 0; r2 < 4; r2++) {
            const int m = wm2 * 128 + i * 16 + quad * 4 + r2;
            unsigned short* hrow = Hbe + (size_t)m * F_;
#pragma unroll
            for (int j = 0; j < 4; j++) {
                const float v = acc[i][j][r2];
                hrow[j * 16 + l15] = f2b(v / (1.f + __expf(-v)));
            }
        }
    }
}

// ---------------- 5. GEMM2: xmlp[be] = H[be] @ w2[e]  (bf16 out, no atomics) ----------------
__global__ __launch_bounds__(512, 2) void gemm2_kernel(
    const unsigned short* __restrict__ H,    // [B*E][KCAP][F] bf16
    const unsigned short* __restrict__ w2t,  // [E][D][F] bf16
    unsigned short* __restrict__ xmlp)       // [B*E][KCAP][D] bf16
{
    const int g  = blockIdx.x;               // 256 = e(8, XCD id) * b(8) * nt(4)
    const int e  = g & 7;
    const int rr = g >> 3;
    const int b  = rr >> 2;
    const int nt = rr & 3;
    const int be = b * 8 + e;
    const int tid = threadIdx.x;
    constexpr int NKT = F_ / 64;             // 32

    __shared__ __align__(16) unsigned short Asm[2 * 2 * 128 * 64];
    __shared__ __align__(16) unsigned short Bsm[2 * 2 * 128 * 64];

    const int r0   = tid >> 3;
    const int kseg = (tid & 7) ^ (r0 & 7);
    const int dst0 = tid * 8;

    const unsigned short* gA = H;
    const unsigned short* gB = w2t;
    unsigned srcA[4], srcB[4];
#pragma unroll
    for (int q = 0; q < 4; q++) {
        const int m = q * 64 + r0;
        srcA[q] = (unsigned)((be * KCAP + m) * F_ + kseg * 8);
        srcB[q] = (unsigned)((e * D_ + nt * 256 + m) * F_ + kseg * 8);
    }

    const int lane = tid & 63;
    const int wv   = tid >> 6;
    const int wm2  = wv >> 2;
    const int wn4  = wv & 3;
    const int l15  = lane & 15;
    const int quad = lane >> 4;
    const int x0   = (quad ^ (l15 & 7)) * 8;
    const int aRd  = wm2 * 8192 + l15 * 64 + x0;
    const int bRd  = (wn4 >> 1) * 8192 + ((wn4 & 1) * 64 + l15) * 64 + x0;

    floatx4 acc[8][4];
#pragma unroll
    for (int i = 0; i < 8; i++)
#pragma unroll
        for (int j = 0; j < 4; j++) acc[i][j] = (floatx4){0.f, 0.f, 0.f, 0.f};
    bf16x8 aF[8][2], bF[4][2];

    PROLOGUE();
    KLOOP();

    // epilogue: plain coalesced bf16 stores (combine kernel applies G and scatters)
    unsigned short* Xbe = xmlp + (size_t)be * KCAP * D_ + (nt * 256 + wn4 * 64);
#pragma unroll
    for (int i = 0; i < 8; i++) {
#pragma unroll
        for (int r2 = 0; r2 < 4; r2++) {
            const int m = wm2 * 128 + i * 16 + quad * 4 + r2;
            unsigned short* orow = Xbe + (size_t)m * D_;
#pragma unroll
            for (int j = 0; j < 4; j++)
                orow[j * 16 + l15] = f2b(acc[i][j][r2]);
        }
    }
}

// ---------------- 6. combine: out[b,s,:] = sum_e Pmap-hit G * xmlp-row (each token written once) -------
__global__ void combine_kernel(const unsigned short* __restrict__ xmlp, // [B*E][KCAP][D] bf16
                               const unsigned short* __restrict__ Pmap, // [B][S][E] slot+1
                               const float* __restrict__ G,             // [B*E][KCAP]
                               float* __restrict__ out) {               // [B][S][D] fp32
    int gid  = blockIdx.x * 256 + threadIdx.x;
    int wave = gid >> 6;                               // token id b*S+s
    int lane = gid & 63;
    int b = wave >> 10;
    float acc[16];
#pragma unroll
    for (int i = 0; i < 16; i++) acc[i] = 0.f;
    const unsigned short* pm = Pmap + (size_t)wave * E_;
#pragma unroll
    for (int e = 0; e < E_; e++) {
        int pe = pm[e];
        if (pe) {
            int beslot = (b * E_ + e) * KCAP + (pe - 1);
            float g = G[beslot];
            const unsigned short* rw = xmlp + (size_t)beslot * D_ + lane * 16;
            ushortx8 r0 = *(const ushortx8*)(rw);
            ushortx8 r1 = *(const ushortx8*)(rw + 8);
#pragma unroll
            for (int i = 0; i < 8; i++) {
                acc[i]     = fmaf(g, b2f(r0[i]), acc[i]);
                acc[8 + i] = fmaf(g, b2f(r1[i]), acc[8 + i]);
            }
        }
    }
    float* orow = out + (size_t)wave * D_ + lane * 16;
    ((float4*)orow)[0] = make_float4(acc[0],  acc[1],  acc[2],  acc[3]);
    ((float4*)orow)[1] = make_float4(acc[4],  acc[5],  acc[6],  acc[7]);
    ((float4*)orow)[2] = make_float4(acc[8],  acc[9],  acc[10], acc[11]);
    ((float4*)orow)[3] = make_float4(acc[12], acc[13], acc[14], acc[15]);
}

// ---------------- launch ----------------
extern "C" void kernel_launch(void* const* d_in, const int* in_sizes, int n_in,
                              void* d_out, int out_size, void* d_ws, size_t ws_size,
                              hipStream_t stream) {
    const float* x  = (const float*)d_in[0];
    const float* cw = (const float*)d_in[1];
    const float* w1 = (const float*)d_in[2];
    const float* w2 = (const float*)d_in[3];
    float* out = (float*)d_out;

    // workspace layout (bytes), total 151,519,232.
    // wT shared between w1t (gemm1) and w2t (gemm2) -- transpose of w2 runs AFTER gemm1.
    char* ws = (char*)d_ws;
    float*          probs = (float*)(ws);                        //   0.26 MB  [B][E][S]
    int*            Ibuf  = (int*)(ws + 262144);                 //  64 KB     [B][E][256]
    float*          Gbuf  = (float*)(ws + 327680);               //  64 KB
    unsigned short* Pmap  = (unsigned short*)(ws + 393216);      // 128 KB     [B][S][E]
    unsigned short* xb    = (unsigned short*)(ws + 524288);      //  16.78 MB  x bf16
    unsigned short* wT    = (unsigned short*)(ws + 17301504);    //  33.55 MB  [E][F][D] then [E][D][F]
    unsigned short* Hbuf  = (unsigned short*)(ws + 50855936);    //  67.11 MB  [B*E][256][F]
    unsigned short* xmlp  = (unsigned short*)(ws + 117964800);   //  33.55 MB  [B*E][256][D]

    router_kernel<<<(B_ * S_ * 64) / 256, 256, 0, stream>>>(x, cw, probs, xb);
    topk_kernel<<<B_ * E_, 256, 0, stream>>>(probs, Ibuf, Gbuf, Pmap);
    transpose_cvt_kernel<<<dim3(F_ / 32, D_ / 32, E_), 256, 0, stream>>>(w1, wT, D_, F_);
    gemm1_kernel<<<B_ * E_ * (F_ / 256), 512, 0, stream>>>(xb, wT, Ibuf, Hbuf);
    transpose_cvt_kernel<<<dim3(D_ / 32, F_ / 32, E_), 256, 0, stream>>>(w2, wT, F_, D_);
    gemm2_kernel<<<B_ * E_ * (D_ / 256), 512, 0, stream>>>(Hbuf, wT, xmlp);
    combine_kernel<<<(B_ * S_ * 64) / 256, 256, 0, stream>>>(xmlp, Pmap, Gbuf, out);
}

// Round 4
// 387.483 us; speedup vs baseline: 1.0824x; 1.0824x over previous
//
#include <hip/hip_runtime.h>
#include <hip/hip_bf16.h>
#include <math.h>

// Problem constants (reference: B=8, S=1024, D=1024, E=8, F=2048, capacity 2 -> k=256)
#define B_   8
#define S_   1024
#define D_   1024
#define E_   8
#define F_   2048
#define KCAP 256

typedef __bf16 bf16x8 __attribute__((ext_vector_type(8)));
typedef float  floatx4 __attribute__((ext_vector_type(4)));
typedef unsigned short ushortx8 __attribute__((ext_vector_type(8)));

// ---- fp32 -> bf16 round-to-nearest-even (no NaN in this data) ----
__device__ __forceinline__ unsigned short f2b(float f) {
    union { float f; unsigned int u; } v; v.f = f;
    unsigned int u = v.u;
    u += 0x7fffu + ((u >> 16) & 1u);
    return (unsigned short)(u >> 16);
}
__device__ __forceinline__ float b2f(unsigned short u) {
    union { unsigned int u; float f; } v; v.u = ((unsigned)u) << 16; return v.f;
}

__device__ __forceinline__ void gl_lds16(const void* g, void* l) {
    __builtin_amdgcn_global_load_lds(
        (const __attribute__((address_space(1))) void*)g,
        (__attribute__((address_space(3))) void*)l, 16, 0, 0);
}

// sortable key: probs > 0 so float bits are monotonic; secondary index asc
// (larger (1023-s) wins ties -> smaller s, matching lax.top_k).
__device__ __forceinline__ unsigned long long topk_key(float p, int s) {
    return (((unsigned long long)__float_as_uint(p)) << 10) | (unsigned)(S_ - 1 - s);
}

// ---------------- 1. router: logits + softmax (fp32) + fused x->bf16 cast (vectorized) ----------------
__global__ void router_kernel(const float* __restrict__ x, const float* __restrict__ cw,
                              float* __restrict__ probs, unsigned short* __restrict__ xb) {
    int gid  = blockIdx.x * 256 + threadIdx.x;
    int wave = gid >> 6;
    int lane = gid & 63;
    int b = wave >> 10;                                // S_=1024
    int s = wave & (S_ - 1);
    const float* xrow = x + ((size_t)b * S_ + s) * D_;
    unsigned short* xbrow = xb + ((size_t)b * S_ + s) * D_;
    float acc[E_];
#pragma unroll
    for (int e = 0; e < E_; e++) acc[e] = 0.f;
#pragma unroll
    for (int it = 0; it < D_ / 256; it++) {
        int i = it * 256 + lane * 4;
        float4 xv = *(const float4*)(xrow + i);
        ushort4 o;
        o.x = f2b(xv.x); o.y = f2b(xv.y); o.z = f2b(xv.z); o.w = f2b(xv.w);
        *(ushort4*)(xbrow + i) = o;                    // fused cast, 8B/lane stores
#pragma unroll
        for (int e = 0; e < E_; e++) {
            float4 wv = *(const float4*)(cw + e * D_ + i);   // 32KB table, L1/L2-resident
            acc[e] = fmaf(xv.x, wv.x, fmaf(xv.y, wv.y, fmaf(xv.z, wv.z, fmaf(xv.w, wv.w, acc[e]))));
        }
    }
#pragma unroll
    for (int e = 0; e < E_; e++) {
        float v = acc[e];
#pragma unroll
        for (int off = 32; off >= 1; off >>= 1) v += __shfl_down(v, off, 64);
        acc[e] = v;
    }
    if (lane == 0) {
        float m = acc[0];
#pragma unroll
        for (int e = 1; e < E_; e++) m = fmaxf(m, acc[e]);
        float sum = 0.f;
#pragma unroll
        for (int e = 0; e < E_; e++) { acc[e] = __expf(acc[e] - m); sum += acc[e]; }
        float inv = 1.f / sum;
#pragma unroll
        for (int e = 0; e < E_; e++) probs[((size_t)b * E_ + e) * S_ + s] = acc[e] * inv;
    }
}

// ---------------- 2. top-k (merged rank + finalize): one block per (b,e) ----------------
__global__ void topk_kernel(const float* __restrict__ probs, int* __restrict__ I,
                            float* __restrict__ G, unsigned short* __restrict__ Pmap) {
    const int be = blockIdx.x;
    const int b = be >> 3, e = be & 7;
    const int tid = threadIdx.x;
    __shared__ unsigned long long keys[S_];
    const float* rowp = probs + (size_t)be * S_;
#pragma unroll
    for (int q = 0; q < 4; q++) {
        const int s = q * 256 + tid;
        keys[s] = topk_key(rowp[s], s);
        Pmap[((size_t)(b * S_ + s)) * E_ + e] = 0;
    }
    __syncthreads();
    unsigned long long my[4];
    int r[4] = {0, 0, 0, 0};
#pragma unroll
    for (int q = 0; q < 4; q++) my[q] = keys[q * 256 + tid];
#pragma unroll 8
    for (int t = 0; t < S_; t++) {
        const unsigned long long kt = keys[t];                 // LDS broadcast
#pragma unroll
        for (int q = 0; q < 4; q++) r[q] += (kt > my[q]);
    }
#pragma unroll
    for (int q = 0; q < 4; q++) {
        if (r[q] < KCAP) {
            const int s = q * 256 + tid;
            I[be * KCAP + r[q]] = s;
            G[be * KCAP + r[q]] = rowp[s];
            Pmap[((size_t)(b * S_ + s)) * E_ + e] = (unsigned short)(r[q] + 1);
        }
    }
}

// ---------------- 3. batched transpose + cast: in [E][R][C] fp32 -> out [E][C][R] bf16 ----------------
__global__ void transpose_cvt_kernel(const float* __restrict__ in, unsigned short* __restrict__ out,
                                     int R, int C) {
    __shared__ float tile[32][33];                    // +1 pad
    int e = blockIdx.z;
    int c0 = blockIdx.x * 32, r0 = blockIdx.y * 32;
    const float* ine = in + (size_t)e * R * C;
    unsigned short* oute = out + (size_t)e * R * C;
    int tid = threadIdx.x;
    int row = tid >> 3, cs = tid & 7;
    float4 v = *(const float4*)(ine + (size_t)(r0 + row) * C + c0 + cs * 4);
    tile[row][cs * 4 + 0] = v.x; tile[row][cs * 4 + 1] = v.y;
    tile[row][cs * 4 + 2] = v.z; tile[row][cs * 4 + 3] = v.w;
    __syncthreads();
    int c = tid >> 3, rq = tid & 7;
    ushort4 o;
    o.x = f2b(tile[rq * 4 + 0][c]); o.y = f2b(tile[rq * 4 + 1][c]);
    o.z = f2b(tile[rq * 4 + 2][c]); o.w = f2b(tile[rq * 4 + 3][c]);
    *(ushort4*)(oute + (size_t)(c0 + c) * R + r0 + rq * 4) = o;
}

// ======== gemm1: 8-phase 256x256 core (3rd submit — rounds 2/3 were infra failures;
// full hang/fault audit redone: uniform barriers, vmcnt ledger closes, RAW/WAR clean,
// all global/LDS offsets bounded). ========
// Fix 1: every s_barrier fenced by sched_barrier(0) both sides (round-1 regression cause:
// compiler re-clustered phases across raw s_barrier).
// Fix 2: balanced ds_reads 12/4/8/0 (quadrant order (0,0),(0,2),(4,2),(4,0)); aF live set
// halved (4 frags, reloaded) -> off the 256-reg cap (round 1 was at cap).
// Fix 3: counted vmcnt(4) at ph4/ph8 only (T4). Ledger (2 loads/STAGE, per-thread):
// prologue issues 12, vmcnt(4) retires tile0's 8; each half-iter issues 8, vmcnt(4)
// retires exactly the next tile's 8. RAW: every read's source half-tile retired before
// the preceding barrier. WAR: every overwrite issued >=1 barrier after its last reader.
// Stage plan (iter = tiles t,t+1; buf = tile parity):
//  ph1 A_hi(t+1)  ph2 B_hi(t+1)  ph3 B_lo(t+2)  ph4 A_lo(t+2)+vmcnt
//  ph5 A_hi(t+2)  ph6 B_hi(t+2)  ph7 B_lo(t+3)  ph8 A_lo(t+3)+vmcnt

#define SB0()  __builtin_amdgcn_sched_barrier(0)
#define BARX() do { SB0(); __builtin_amdgcn_s_barrier(); SB0(); } while (0)

#define LDA_SET(SET, BUF) do { \
    _Pragma("unroll") \
    for (int ii = 0; ii < 4; ii++) { \
        const int o_ = (BUF) * 16384 + aRd + ((SET) + ii) * 1024; \
        aF[ii][0] = *(const bf16x8*)&Asm[o_]; \
        aF[ii][1] = *(const bf16x8*)&Asm[o_ ^ 32]; \
    } } while (0)

#define LDB_SET(J0, BUF) do { \
    _Pragma("unroll") \
    for (int jj = 0; jj < 2; jj++) { \
        const int o_ = (BUF) * 16384 + bRd + ((J0) + jj) * 1024; \
        bF[(J0) + jj][0] = *(const bf16x8*)&Bsm[o_]; \
        bF[(J0) + jj][1] = *(const bf16x8*)&Bsm[o_ ^ 32]; \
    } } while (0)

#define MMQ(I0, J0) do { \
    __builtin_amdgcn_s_setprio(1); \
    _Pragma("unroll") \
    for (int ii = 0; ii < 4; ii++) \
    _Pragma("unroll") \
    for (int jj = 0; jj < 2; jj++) { \
        acc[(I0)+ii][(J0)+jj] = __builtin_amdgcn_mfma_f32_16x16x32_bf16(aF[ii][0], bF[(J0)+jj][0], acc[(I0)+ii][(J0)+jj], 0, 0, 0); \
        acc[(I0)+ii][(J0)+jj] = __builtin_amdgcn_mfma_f32_16x16x32_bf16(aF[ii][1], bF[(J0)+jj][1], acc[(I0)+ii][(J0)+jj], 0, 0, 0); \
    } \
    __builtin_amdgcn_s_setprio(0); \
} while (0)

#define STAGE_A(T, HH) do { if ((T) < NKT) { \
    const unsigned k_ = (unsigned)(T) * 64u; \
    const int d_ = ((((T) & 1) * 2 + (HH)) * 8192) + dst0; \
    gl_lds16(gA + srcA[(HH) * 2 + 0] + k_, &Asm[d_]); \
    gl_lds16(gA + srcA[(HH) * 2 + 1] + k_, &Asm[d_ + 4096]); \
} } while (0)

#define STAGE_B(T, HH) do { if ((T) < NKT) { \
    const unsigned k_ = (unsigned)(T) * 64u; \
    const int d_ = ((((T) & 1) * 2 + (HH)) * 8192) + dst0; \
    gl_lds16(gB + srcB[(HH) * 2 + 0] + k_, &Bsm[d_]); \
    gl_lds16(gB + srcB[(HH) * 2 + 1] + k_, &Bsm[d_ + 4096]); \
} } while (0)

// ---------------- 4. GEMM1: H[be] = silu(gather(x, I[be]) @ w1[e]) ----------------
__global__ __launch_bounds__(512, 2) void gemm1_kernel(
    const unsigned short* __restrict__ xb,   // [B][S][D] bf16
    const unsigned short* __restrict__ w1t,  // [E][F][D] bf16
    const int* __restrict__ Ibuf,            // [B][E][KCAP]
    unsigned short* __restrict__ H)          // [B*E][KCAP][F] bf16
{
    const int g  = blockIdx.x;               // 512 = e(8, XCD id) * b(8) * nt(8)
    const int e  = g & 7;
    const int rr = g >> 3;
    const int b  = rr >> 3;
    const int nt = rr & 7;
    const int be = b * 8 + e;
    const int tid = threadIdx.x;
    constexpr int NKT = D_ / 64;             // 16

    __shared__ __align__(16) unsigned short Asm[2 * 2 * 128 * 64];  // 64 KB
    __shared__ __align__(16) unsigned short Bsm[2 * 2 * 128 * 64];  // 64 KB

    const int r0   = tid >> 3;               // 0..63
    const int kseg = (tid & 7) ^ (r0 & 7);   // permuted 16B segment
    const int dst0 = tid * 8;                // LDS elem offset

    const unsigned short* gA = xb;
    const unsigned short* gB = w1t;
    unsigned srcA[4], srcB[4];               // rows r0 + {0,64,128,192}
#pragma unroll
    for (int q = 0; q < 4; q++) {
        const int m = q * 64 + r0;
        const int tok = Ibuf[be * KCAP + m];
        srcA[q] = (unsigned)((b * S_ + tok) * D_ + kseg * 8);
        srcB[q] = (unsigned)((e * F_ + nt * 256 + m) * D_ + kseg * 8);
    }

    const int lane = tid & 63;
    const int wv   = tid >> 6;
    const int wm2  = wv >> 2;                // 0..1
    const int wn4  = wv & 3;                 // 0..3
    const int l15  = lane & 15;
    const int quad = lane >> 4;
    const int x0   = (quad ^ (l15 & 7)) * 8;
    const int aRd  = wm2 * 8192 + l15 * 64 + x0;                    // + buf*16384 + i*1024
    const int bRd  = (wn4 >> 1) * 8192 + ((wn4 & 1) * 64 + l15) * 64 + x0;

    floatx4 acc[8][4];
#pragma unroll
    for (int i = 0; i < 8; i++)
#pragma unroll
        for (int j = 0; j < 4; j++) acc[i][j] = (floatx4){0.f, 0.f, 0.f, 0.f};
    bf16x8 aF[4][2], bF[4][2];

    // prologue: tile0 fully + tile1 lo halves; drain to 4 -> tile0 landed.
    STAGE_A(0, 0); STAGE_A(0, 1); STAGE_B(0, 0); STAGE_B(0, 1);
    STAGE_B(1, 0); STAGE_A(1, 0);
    asm volatile("s_waitcnt vmcnt(4)" ::: "memory");
    BARX();

#pragma unroll 1
    for (int t = 0; t < NKT; t += 2) {
        // ph1
        LDA_SET(0, 0); LDB_SET(0, 0); STAGE_A(t + 1, 1);
        BARX(); MMQ(0, 0); BARX();
        // ph2
        LDB_SET(2, 0); STAGE_B(t + 1, 1);
        BARX(); MMQ(0, 2); BARX();
        // ph3
        LDA_SET(4, 0); STAGE_B(t + 2, 0);
        BARX(); MMQ(4, 2); BARX();
        // ph4
        STAGE_A(t + 2, 0);
        if (t + 2 < NKT) { asm volatile("s_waitcnt vmcnt(4)" ::: "memory"); }
        else             { asm volatile("s_waitcnt vmcnt(0)" ::: "memory"); }
        BARX(); MMQ(4, 0); BARX();
        // ph5
        LDA_SET(0, 1); LDB_SET(0, 1); STAGE_A(t + 2, 1);
        BARX(); MMQ(0, 0); BARX();
        // ph6
        LDB_SET(2, 1); STAGE_B(t + 2, 1);
        BARX(); MMQ(0, 2); BARX();
        // ph7
        LDA_SET(4, 1); STAGE_B(t + 3, 0);
        BARX(); MMQ(4, 2); BARX();
        // ph8
        STAGE_A(t + 3, 0);
        asm volatile("s_waitcnt vmcnt(4)" ::: "memory");
        BARX(); MMQ(4, 0); BARX();
    }

    // epilogue: silu -> H (bf16). C/D layout: row = quad*4+r, col = lane&15 (m89-verified)
    unsigned short* Hbe = H + (size_t)be * KCAP * F_ + (nt * 256 + wn4 * 64);
#pragma unroll
    for (int i = 0; i < 8; i++) {
#pragma unroll
        for (int r2 = 0; r2 < 4; r2++) {
            const int m = wm2 * 128 + i * 16 + quad * 4 + r2;
            unsigned short* hrow = Hbe + (size_t)m * F_;
#pragma unroll
            for (int j = 0; j < 4; j++) {
                const float v = acc[i][j][r2];
                hrow[j * 16 + l15] = f2b(v / (1.f + __expf(-v)));
            }
        }
    }
}

// ---------------- 5. GEMM2 (round-0 verified 128x128 structure, 880 TF) ----------------
__global__ __launch_bounds__(256, 4) void gemm2_kernel(
    const unsigned short* __restrict__ H,    // [B*E][KCAP][F] bf16
    const unsigned short* __restrict__ w2t,  // [E][D][F] bf16
    unsigned short* __restrict__ xmlp)       // [B*E][KCAP][D] bf16
{
    const int g  = blockIdx.x;               // 1024 = 8 xcd * 8 b * 16 tiles
    const int e  = g & 7;                    // XCD id
    const int rr = g >> 3;
    const int b  = rr >> 4;
    const int t4 = rr & 15;
    const int be = b * 8 + e;
    const int mt = t4 & 1;          // 2 m-tiles
    const int nt = t4 >> 1;         // 8 n-tiles (1024/128)
    const int tid = threadIdx.x;

    __shared__ __align__(16) unsigned short Asm2[128 * 64];
    __shared__ __align__(16) unsigned short Bsm2[128 * 64];

    const int r8   = tid >> 3;
    const int kseg = (tid & 7) ^ (r8 & 7);
    const size_t aoff0 = ((size_t)be * KCAP + mt * 128 + r8) * F_ + kseg * 8;
    const size_t boff0 = ((size_t)e * D_ + nt * 128 + r8) * F_ + kseg * 8;

    const int lane = tid & 63;
    const int wv   = tid >> 6;
    const int wm   = (wv & 1) * 64;
    const int wn   = (wv >> 1) * 64;
    const int l15  = lane & 15;
    const int quad = lane >> 4;
    const int x0   = (quad ^ (l15 & 7)) * 8;

    int aoffs[4], boffs[4];
#pragma unroll
    for (int i = 0; i < 4; i++) {
        aoffs[i] = (wm + i * 16 + l15) * 64 + x0;
        boffs[i] = (wn + i * 16 + l15) * 64 + x0;
    }

    floatx4 acc[4][4];
#pragma unroll
    for (int i = 0; i < 4; i++)
#pragma unroll
        for (int j = 0; j < 4; j++) acc[i][j] = (floatx4){0.f, 0.f, 0.f, 0.f};

    for (int k0 = 0; k0 < F_; k0 += 64) {
#pragma unroll
        for (int w = 0; w < 4; w++) {
            gl_lds16(H   + aoff0 + (size_t)w * 32 * F_ + k0, &Asm2[(w * 256 + tid) * 8]);
            gl_lds16(w2t + boff0 + (size_t)w * 32 * F_ + k0, &Bsm2[(w * 256 + tid) * 8]);
        }
        __syncthreads();
        bf16x8 af[4], bfr[4];
#pragma unroll
        for (int i = 0; i < 4; i++) {
            af[i]  = *(const bf16x8*)&Asm2[aoffs[i]];
            bfr[i] = *(const bf16x8*)&Bsm2[boffs[i]];
        }
#pragma unroll
        for (int i = 0; i < 4; i++)
#pragma unroll
            for (int j = 0; j < 4; j++)
                acc[i][j] = __builtin_amdgcn_mfma_f32_16x16x32_bf16(af[i], bfr[j], acc[i][j], 0, 0, 0);
#pragma unroll
        for (int i = 0; i < 4; i++) {
            af[i]  = *(const bf16x8*)&Asm2[aoffs[i] ^ 32];
            bfr[i] = *(const bf16x8*)&Bsm2[boffs[i] ^ 32];
        }
#pragma unroll
        for (int i = 0; i < 4; i++)
#pragma unroll
            for (int j = 0; j < 4; j++)
                acc[i][j] = __builtin_amdgcn_mfma_f32_16x16x32_bf16(af[i], bfr[j], acc[i][j], 0, 0, 0);
        __syncthreads();
    }

    // epilogue: plain coalesced bf16 stores (combine kernel applies G and scatters)
    unsigned short* Xbe = xmlp + (size_t)be * KCAP * D_;
#pragma unroll
    for (int i = 0; i < 4; i++) {
#pragma unroll
        for (int r = 0; r < 4; r++) {
            int m = mt * 128 + wm + i * 16 + quad * 4 + r;
            unsigned short* orow = Xbe + (size_t)m * D_ + nt * 128;
#pragma unroll
            for (int j = 0; j < 4; j++)
                orow[wn + j * 16 + l15] = f2b(acc[i][j][r]);
        }
    }
}

// ---------------- 6. combine: out[b,s,:] = sum_e Pmap-hit G * xmlp-row ----------------
__global__ void combine_kernel(const unsigned short* __restrict__ xmlp, // [B*E][KCAP][D] bf16
                               const unsigned short* __restrict__ Pmap, // [B][S][E] slot+1
                               const float* __restrict__ G,             // [B*E][KCAP]
                               float* __restrict__ out) {               // [B][S][D] fp32
    int gid  = blockIdx.x * 256 + threadIdx.x;
    int wave = gid >> 6;                               // token id b*S+s
    int lane = gid & 63;
    int b = wave >> 10;
    float acc[16];
#pragma unroll
    for (int i = 0; i < 16; i++) acc[i] = 0.f;
    const unsigned short* pm = Pmap + (size_t)wave * E_;
#pragma unroll
    for (int e = 0; e < E_; e++) {
        int pe = pm[e];
        if (pe) {
            int beslot = (b * E_ + e) * KCAP + (pe - 1);
            float g = G[beslot];
            const unsigned short* rw = xmlp + (size_t)beslot * D_ + lane * 16;
            ushortx8 r0 = *(const ushortx8*)(rw);
            ushortx8 r1 = *(const ushortx8*)(rw + 8);
#pragma unroll
            for (int i = 0; i < 8; i++) {
                acc[i]     = fmaf(g, b2f(r0[i]), acc[i]);
                acc[8 + i] = fmaf(g, b2f(r1[i]), acc[8 + i]);
            }
        }
    }
    float* orow = out + (size_t)wave * D_ + lane * 16;
    ((float4*)orow)[0] = make_float4(acc[0],  acc[1],  acc[2],  acc[3]);
    ((float4*)orow)[1] = make_float4(acc[4],  acc[5],  acc[6],  acc[7]);
    ((float4*)orow)[2] = make_float4(acc[8],  acc[9],  acc[10], acc[11]);
    ((float4*)orow)[3] = make_float4(acc[12], acc[13], acc[14], acc[15]);
}

// ---------------- launch ----------------
extern "C" void kernel_launch(void* const* d_in, const int* in_sizes, int n_in,
                              void* d_out, int out_size, void* d_ws, size_t ws_size,
                              hipStream_t stream) {
    const float* x  = (const float*)d_in[0];
    const float* cw = (const float*)d_in[1];
    const float* w1 = (const float*)d_in[2];
    const float* w2 = (const float*)d_in[3];
    float* out = (float*)d_out;

    // workspace layout (bytes), total 151,519,232.
    // wT shared between w1t (gemm1) and w2t (gemm2) -- transpose of w2 runs AFTER gemm1.
    char* ws = (char*)d_ws;
    float*          probs = (float*)(ws);                        //   0.26 MB  [B][E][S]
    int*            Ibuf  = (int*)(ws + 262144);                 //  64 KB     [B][E][256]
    float*          Gbuf  = (float*)(ws + 327680);               //  64 KB
    unsigned short* Pmap  = (unsigned short*)(ws + 393216);      // 128 KB     [B][S][E]
    unsigned short* xb    = (unsigned short*)(ws + 524288);      //  16.78 MB  x bf16
    unsigned short* wT    = (unsigned short*)(ws + 17301504);    //  33.55 MB  [E][F][D] then [E][D][F]
    unsigned short* Hbuf  = (unsigned short*)(ws + 50855936);    //  67.11 MB  [B*E][256][F]
    unsigned short* xmlp  = (unsigned short*)(ws + 117964800);   //  33.55 MB  [B*E][256][D]

    router_kernel<<<(B_ * S_ * 64) / 256, 256, 0, stream>>>(x, cw, probs, xb);
    topk_kernel<<<B_ * E_, 256, 0, stream>>>(probs, Ibuf, Gbuf, Pmap);
    transpose_cvt_kernel<<<dim3(F_ / 32, D_ / 32, E_), 256, 0, stream>>>(w1, wT, D_, F_);
    gemm1_kernel<<<B_ * E_ * (F_ / 256), 512, 0, stream>>>(xb, wT, Ibuf, Hbuf);
    transpose_cvt_kernel<<<dim3(D_ / 32, F_ / 32, E_), 256, 0, stream>>>(w2, wT, F_, D_);
    gemm2_kernel<<<B_ * E_ * 2 * (D_ / 128), 256, 0, stream>>>(Hbuf, wT, xmlp);
    combine_kernel<<<(B_ * S_ * 64) / 256, 256, 0, stream>>>(xmlp, Pmap, Gbuf, out);
}